// Round 9
// baseline (335.544 us; speedup 1.0000x reference)
//
#include <hip/hip_runtime.h>

// Partial-CRF NLL, producer/consumer scan, MX-fp8 K=128, chain-uniform
// power-of-2 rescale broadcast via an 8th MFMA tile (replicated tag-1 row).
// 64 blocks x 192 threads = {wave0: consumer, wave1+2: producers}.
// Block owns 16 chains = 8 batches x {all-paths, gold}.
//
// Representation: true P = stored_fp8 x 2^eSum (uniform per chain; eSum int,
// identical across the chain's 4 lanes by construction). Tile 7's A rows are
// all E[.][1], so D7 gives every lane w1pre = (next P[1])/mult1; each lane
// multiplies by its own f32 exp(emit[t][1]) (prefetched; identical within the
// chain) -> ex = ilogb(w1) locally; csf = 2^-ex exact. NO cross-lane ops in
// the scan loop. stored[1] ~ [1,2); others clamped at 440 (R7-proven).
// mult (bf16 slabs) prefetched one step ahead into f32 regs fA/fB.
// Producers: exp(emit) (gold rows x um) -> bf16 16-slab ring (28-tag windows
// padded to 32). Sync: monotonic LDS flags, volatile polls, lgkmcnt fences.

typedef short s16x4 __attribute__((ext_vector_type(4)));
typedef short s16x8 __attribute__((ext_vector_type(8)));
typedef float f32x4 __attribute__((ext_vector_type(4)));
typedef int   i32x8 __attribute__((ext_vector_type(8)));

constexpr int T = 512, L = 102;
constexpr int MS = 136;        // slab row stride (shorts)
constexpr int NS = 16;         // ring slabs
constexpr int SLAB = 16 * MS;  // shorts per slab

__device__ __forceinline__ float bf2f(short s) {
  return __uint_as_float(((unsigned)(unsigned short)s) << 16);
}
__device__ __forceinline__ float fp8tof(unsigned b) {  // e4m3fn, sign=0
  const int e = (b >> 3) & 15, m = b & 7;
  return e ? ldexpf((float)(8 + m), e - 10) : ldexpf((float)m, -9);
}

#define SC1 0x7F7F7F7F

// one tile epilogue: w = D*mult*csf, clamp 440, pack fp8, masked update
#define ETILE(Tt, FU)                                                        \
  {                                                                          \
    float w0 = dd[Tt][0] * FU[4 * Tt + 0];                                   \
    float w1 = dd[Tt][1] * FU[4 * Tt + 1];                                   \
    float w2 = dd[Tt][2] * FU[4 * Tt + 2];                                   \
    float w3 = dd[Tt][3] * FU[4 * Tt + 3];                                   \
    w0 = fminf(w0 * csf, 440.f); w1 = fminf(w1 * csf, 440.f);                \
    w2 = fminf(w2 * csf, 440.f); w3 = fminf(w3 * csf, 440.f);                \
    int d_ = __builtin_amdgcn_cvt_pk_fp8_f32(w0, w1, 0, false);              \
    d_ = __builtin_amdgcn_cvt_pk_fp8_f32(w2, w3, d_, true);                  \
    pk[Tt] = mmv ? (unsigned)d_ : pk[Tt];                                    \
  }

// One scan step t. SBn: slab byte-offset for t+1 (prefetch into FL);
// TN: clamped t+1 for the e1 global prefetch; FU: mult regs for this step.
#define STEP(SBn, TN, MMVv, FU, FL)                                          \
  {                                                                          \
    const bool mmv = (MMVv) != 0;                                            \
    const float e1v = __expf(e1raw);       /* exp(emit[t][1]), f32 */        \
    const short* sln = mlb + (SBn) + c * MS + 32 * hi;                       \
    const s16x8 N0 = *(const s16x8*)(sln + 0);                               \
    const s16x8 N1 = *(const s16x8*)(sln + 8);                               \
    const s16x8 N2 = *(const s16x8*)(sln + 16);                              \
    const s16x4 N3 = *(const s16x4*)(sln + 24);                              \
    e1raw = e1p[(size_t)(TN) * L];         /* prefetch e1 for t+1 */         \
    i32x8 bb;                                                                \
    bb[0] = (int)pk[0]; bb[1] = (int)pk[1]; bb[2] = (int)pk[2];              \
    bb[3] = (int)pk[3]; bb[4] = (int)pk[4]; bb[5] = (int)pk[5];              \
    bb[6] = (int)pk[6]; bb[7] = 0;                                           \
    const f32x4 d7 = __builtin_amdgcn_mfma_scale_f32_16x16x128_f8f6f4(       \
        ea[7], bb, zf, 0, 0, 0, SC1, 0, SC1);   /* tag-1 row first */        \
    f32x4 dd[7];                                                             \
    dd[0] = __builtin_amdgcn_mfma_scale_f32_16x16x128_f8f6f4(                \
        ea[0], bb, zf, 0, 0, 0, SC1, 0, SC1);                                \
    dd[1] = __builtin_amdgcn_mfma_scale_f32_16x16x128_f8f6f4(                \
        ea[1], bb, zf, 0, 0, 0, SC1, 0, SC1);                                \
    dd[2] = __builtin_amdgcn_mfma_scale_f32_16x16x128_f8f6f4(                \
        ea[2], bb, zf, 0, 0, 0, SC1, 0, SC1);                                \
    dd[3] = __builtin_amdgcn_mfma_scale_f32_16x16x128_f8f6f4(                \
        ea[3], bb, zf, 0, 0, 0, SC1, 0, SC1);                                \
    dd[4] = __builtin_amdgcn_mfma_scale_f32_16x16x128_f8f6f4(                \
        ea[4], bb, zf, 0, 0, 0, SC1, 0, SC1);                                \
    dd[5] = __builtin_amdgcn_mfma_scale_f32_16x16x128_f8f6f4(                \
        ea[5], bb, zf, 0, 0, 0, SC1, 0, SC1);                                \
    dd[6] = __builtin_amdgcn_mfma_scale_f32_16x16x128_f8f6f4(                \
        ea[6], bb, zf, 0, 0, 0, SC1, 0, SC1);                                \
    const float w1 = d7[0] * e1v;          /* next P[1], pre-normalize */    \
    const int ex = (int)(__float_as_uint(w1) >> 23) - 127;                   \
    const float csf = __uint_as_float((unsigned)(127 - ex) << 23);           \
    eSum += mmv ? ex : 0;                                                    \
    ETILE(0, FU) ETILE(1, FU) ETILE(2, FU) ETILE(3, FU)                      \
    ETILE(4, FU) ETILE(5, FU) ETILE(6, FU)                                   \
    _Pragma("unroll") for (int i = 0; i < 8; ++i) FL[i]      = bf2f(N0[i]);  \
    _Pragma("unroll") for (int i = 0; i < 8; ++i) FL[8 + i]  = bf2f(N1[i]);  \
    _Pragma("unroll") for (int i = 0; i < 8; ++i) FL[16 + i] = bf2f(N2[i]);  \
    _Pragma("unroll") for (int i = 0; i < 4; ++i) FL[24 + i] = bf2f(N3[i]);  \
  }

__global__ __launch_bounds__(192, 1)
void crf_scan(const float* __restrict__ emit,
              const float* __restrict__ trans,
              const unsigned char* __restrict__ mask_b,
              const unsigned char* __restrict__ um_b,
              float* __restrict__ partials)
{
  const int tid = threadIdx.x, wid = tid >> 6, lane = tid & 63;
  const int b8 = blockIdx.x * 8;
  // bool layout: um[0,0,1] always True -> byte1==1 iff uint8, else LE int32
  const int ush = (um_b[1] != 0) ? 0 : 2;

  __shared__ __align__(16) short Ml[NS][16][MS];
  __shared__ unsigned char Kmask[8][T];
  __shared__ int sflags[3];   // [0],[1]: producer progress; [2]: consumer

  volatile int* pf0 = (volatile int*)&sflags[0];
  volatile int* pf1 = (volatile int*)&sflags[1];
  volatile int* cfv = (volatile int*)&sflags[2];

  if (wid != 0) {
    // ===================== producer waves (wid 1,2) =====================
    const int pw   = wid - 1;
    const int boff = pw * 4;                       // my 4 batches
    const int tagp = 2 * lane;                     // tag pair (tagp, tagp+1)
    const int tagc = (tagp <= 100) ? tagp : 100;
    const bool tv  = (tagp <= 100);
    // slab short-offset of this tag pair (28-tag windows padded to 32)
    const int woff = 32 * (tagp / 28) + (tagp - 28 * (tagp / 28));
    const bool wok = (tagp < 112);                 // windows 0..3 only

    for (int i = lane; i < 4 * T; i += 64) {       // my Kmask rows
      const int bb = i >> 9, tt = i & 511;
      Kmask[boff + bb][tt] =
          mask_b[(((size_t)(b8 + boff + bb)) * T + tt) << ush];
    }

    struct SetS { float2 e[4]; int u0[4]; int u1[4]; };
    SetS sA, sB, sC, sD;                           // static names

    auto issue = [&](int t, SetS& S) {
      const int tc = (t < T) ? t : T - 1;
#pragma unroll
      for (int i = 0; i < 4; ++i) {
        const size_t base = ((size_t)(b8 + boff + i) * T + tc) * (size_t)L;
        S.e[i] = *(const float2*)(emit + base + tagc);
        if (ush == 0) {
          const unsigned short us = *(const unsigned short*)(um_b + base + tagc);
          S.u0[i] = us & 255; S.u1[i] = us >> 8;
        } else {
          const uint2 uv = *(const uint2*)(um_b + ((base + tagc) << 2));
          S.u0[i] = (int)uv.x; S.u1[i] = (int)uv.y;
        }
      }
    };
    auto stagewr = [&](int t, SetS& S) {
      short* slab = &Ml[t & (NS - 1)][0][0];
#pragma unroll
      for (int i = 0; i < 4; ++i) {
        const float e0 = tv ? __expf(S.e[i].x) : 0.f;
        const float e1 = tv ? __expf(S.e[i].y) : 0.f;
        const float g0 = S.u0[i] ? e0 : 0.f;
        const float g1 = S.u1[i] ? e1 : 0.f;
        unsigned pe, pg;
        asm("v_cvt_pk_bf16_f32 %0, %1, %2" : "=v"(pe) : "v"(e0), "v"(e1));
        asm("v_cvt_pk_bf16_f32 %0, %1, %2" : "=v"(pg) : "v"(g0), "v"(g1));
        if (wok) {
          *(unsigned*)(slab + (2 * (boff + i))     * MS + woff) = pe;  // all
          *(unsigned*)(slab + (2 * (boff + i) + 1) * MS + woff) = pg;  // gold
        }
      }
    };

    __syncthreads();
    issue(1, sA); issue(2, sB); issue(3, sC); issue(4, sD);
    int csn = 0;
    volatile int* myf = (pw == 0) ? pf0 : pf1;

#define PB(tt, S)                                              \
    {                                                          \
      if ((tt) > NS && csn < (tt) - NS) {                      \
        int v; do { v = *cfv; } while (v < (tt) - NS);         \
        csn = v;                                               \
      }                                                        \
      stagewr((tt), S);                                        \
      asm volatile("s_waitcnt lgkmcnt(0)" ::: "memory");       \
      if (lane == 0) *myf = (tt);                              \
      issue((tt) + 4, S);                                      \
    }
    for (int t0 = 1; t0 <= 505; t0 += 4) {
      PB(t0, sA) PB(t0 + 1, sB) PB(t0 + 2, sC) PB(t0 + 3, sD)
    }
    PB(509, sA) PB(510, sB) PB(511, sC)
#undef PB
  } else {
    // ========================= consumer wave =========================
    if (lane == 0) { sflags[0] = 0; sflags[1] = 0; sflags[2] = 0; }
    const int c = lane & 15, hi = lane >> 4;
    const int myb = c >> 1, batch = b8 + myb, goldc = c & 1;

    // A-frags fp8. Tiles 0..6: row c -> out-tag 28*(c>>2)+4*Tt+(c&3);
    // tile 7: all rows = E[.][1] (w1 broadcast). Byte j -> k-tag 28*hi+j.
    i32x8 ea[8];
#pragma unroll
    for (int Tt = 0; Tt < 8; ++Tt) {
      const int gA = (Tt < 7) ? (28 * (c >> 2) + 4 * Tt + (c & 3)) : 1;
#pragma unroll
      for (int d8 = 0; d8 < 8; ++d8) {
        float v0 = 0.f, v1 = 0.f, v2 = 0.f, v3 = 0.f;
#pragma unroll
        for (int bq = 0; bq < 4; ++bq) {
          const int j = 4 * d8 + bq, ktag = 28 * hi + j;
          float e = 0.f;
          if (j < 28 && ktag < L && gA < L) e = __expf(trans[ktag * L + gA]);
          if (bq == 0) v0 = e; else if (bq == 1) v1 = e;
          else if (bq == 2) v2 = e; else v3 = e;
        }
        int dw = __builtin_amdgcn_cvt_pk_fp8_f32(v0, v1, 0, false);
        dw = __builtin_amdgcn_cvt_pk_fp8_f32(v2, v3, dw, true);
        ea[Tt][d8] = dw;
      }
    }

    // t = 0 init: P0 = exp(e0 + trans[START][tag]) (gold: um-gated),
    // normalized by 2^-ex0, ex0 = ilogb(P0[1]); eSum = ex0 (uniform/chain).
    unsigned pk[7];
    int eSum;
    const size_t e0b = (size_t)batch * T * L;
    {
      const float p01 = __expf(emit[e0b + 1] + trans[100 * L + 1]);
      const int ex0 = (int)(__float_as_uint(p01) >> 23) - 127;
      const float cs0 = __uint_as_float((unsigned)(127 - ex0) << 23);
      eSum = ex0;
#pragma unroll
      for (int Tt = 0; Tt < 7; ++Tt) {
        float w[4];
#pragma unroll
        for (int r = 0; r < 4; ++r) {
          const int tg = 28 * hi + 4 * Tt + r;
          float x = 0.f;
          if (tg < L) {
            x = __expf(emit[e0b + tg] + trans[100 * L + tg]);
            if (goldc && !um_b[(e0b + tg) << ush]) x = 0.f;
          }
          w[r] = fminf(x * cs0, 440.f);
        }
        int dw = __builtin_amdgcn_cvt_pk_fp8_f32(w[0], w[1], 0, false);
        dw = __builtin_amdgcn_cvt_pk_fp8_f32(w[2], w[3], dw, true);
        pk[Tt] = (unsigned)dw;
      }
    }

    const short* mlb = &Ml[0][0][0];
    const unsigned* kmr = (const unsigned*)&Kmask[myb][0];
    const float* e1p = emit + e0b + 1;       // emit[batch][t][1] at e1p[t*L]
    const f32x4 zf = {0.f, 0.f, 0.f, 0.f};
    float fA[28], fB[28];
    float e1raw;
    int seen = 0;

    __syncthreads();

    {   // preload fA (slab t=1) + e1raw for t=1
      int v0, v1;
      do { v0 = *pf0; v1 = *pf1; } while (v0 < 1 || v1 < 1);
      seen = (v0 < v1) ? v0 : v1;
      int sb1 = SLAB;
      asm volatile("" : "+v"(sb1) : "v"(seen));
      const short* sln = mlb + sb1 + c * MS + 32 * hi;
      const s16x8 N0 = *(const s16x8*)(sln + 0);
      const s16x8 N1 = *(const s16x8*)(sln + 8);
      const s16x8 N2 = *(const s16x8*)(sln + 16);
      const s16x4 N3 = *(const s16x4*)(sln + 24);
#pragma unroll
      for (int i = 0; i < 8; ++i) fA[i] = bf2f(N0[i]);
#pragma unroll
      for (int i = 0; i < 8; ++i) fA[8 + i] = bf2f(N1[i]);
#pragma unroll
      for (int i = 0; i < 8; ++i) fA[16 + i] = bf2f(N2[i]);
#pragma unroll
      for (int i = 0; i < 4; ++i) fA[24 + i] = bf2f(N3[i]);
      e1raw = e1p[(size_t)1 * L];
    }

    for (int t0 = 1; t0 <= 505; t0 += 4) {
      const int pt = (t0 + 4 < 511) ? t0 + 4 : 511;
      if (seen < pt) {
        int v0, v1;
        do { v0 = *pf0; v1 = *pf1; } while (v0 < pt || v1 < pt);
        seen = (v0 < v1) ? v0 : v1;
      }
      int sb1 = ((t0 + 1) & 15) * SLAB;
      int sb2 = ((t0 + 2) & 15) * SLAB;
      int sb3 = ((t0 + 3) & 15) * SLAB;
      int sb4 = ((t0 + 4) & 15) * SLAB;
      asm volatile("" : "+v"(sb1), "+v"(sb2), "+v"(sb3), "+v"(sb4)
                   : "v"(seen));
      const unsigned kl = kmr[(t0 - 1) >> 2];          // bytes t0-1..t0+2
      const unsigned kh = kmr[((t0 - 1) >> 2) + 1];    // byte  t0+3
      const unsigned m0 = (kl >> 8) & 255u, m1 = (kl >> 16) & 255u;
      const unsigned m2 = kl >> 24,         m3 = kh & 255u;
      STEP(sb1, t0 + 1, m0, fA, fB)
      STEP(sb2, t0 + 2, m1, fB, fA)
      STEP(sb3, t0 + 3, m2, fA, fB)
      STEP(sb4, t0 + 4, m3, fB, fA)
      asm volatile("s_waitcnt lgkmcnt(0)" ::: "memory");
      if (lane == 0) *cfv = t0 + 3;
    }
    {   // tail t = 509..511
      if (seen < 511) {
        int v0, v1;
        do { v0 = *pf0; v1 = *pf1; } while (v0 < 511 || v1 < 511);
        seen = (v0 < v1) ? v0 : v1;
      }
      int sbB = 14 * SLAB, sbC = 15 * SLAB;
      asm volatile("" : "+v"(sbB), "+v"(sbC) : "v"(seen));
      const unsigned kl = kmr[127];                    // bytes 508..511
      const unsigned m0 = (kl >> 8) & 255u, m1 = (kl >> 16) & 255u;
      const unsigned m2 = kl >> 24;
      STEP(sbB, 510, m0, fA, fB)     // t=509, prefetch slab 510
      STEP(sbC, 511, m1, fB, fA)     // t=510, prefetch slab 511
      STEP(sbC, 511, m2, fA, fB)     // t=511, dummy prefetch
    }

    // final: tot = sum_tag stored * exp(trans[tag][STOP]) over lane's 28
    // tags; sum across the chain's 4 hi-lanes; score = eSum*ln2 + log(tot).
    float tot = 0.f;
#pragma unroll
    for (int Tt = 0; Tt < 7; ++Tt) {
#pragma unroll
      for (int r = 0; r < 4; ++r) {
        const int tg = 28 * hi + 4 * Tt + r;
        if (tg < L) {
          const unsigned pb = (pk[Tt] >> (8 * r)) & 255u;
          tot += fp8tof(pb) * __expf(trans[tg * L + 101]);
        }
      }
    }
    tot += __shfl_xor(tot, 16);
    tot += __shfl_xor(tot, 32);
    const float score = (float)eSum * 0.6931471805599453f + __logf(tot);
    float sgn = goldc ? -score : score;
    sgn += __shfl_xor(sgn, 1);
    sgn += __shfl_xor(sgn, 2);
    sgn += __shfl_xor(sgn, 4);
    sgn += __shfl_xor(sgn, 8);
    if (lane == 0) partials[blockIdx.x] = sgn;
  }
}

__global__ void reduce_partials(const float* __restrict__ part,
                                float* __restrict__ out) {
  float v = part[threadIdx.x];
#pragma unroll
  for (int s = 1; s < 64; s <<= 1) v += __shfl_xor(v, s);
  if (threadIdx.x == 0) out[0] = v;
}

extern "C" void kernel_launch(void* const* d_in, const int* in_sizes, int n_in,
                              void* d_out, int out_size, void* d_ws,
                              size_t ws_size, hipStream_t stream) {
  const float* emit = (const float*)d_in[0];
  const float* trn  = (const float*)d_in[1];
  const unsigned char* msk = (const unsigned char*)d_in[2];
  const unsigned char* umk = (const unsigned char*)d_in[3];
  float* out = (float*)d_out;
  float* pw  = (float*)d_ws;   // 64 block partials

  crf_scan<<<dim3(64), dim3(192), 0, stream>>>(emit, trn, msk, umk, pw);
  reduce_partials<<<dim3(1), dim3(64), 0, stream>>>(pw, out);
}

// Round 11
// 315.092 us; speedup vs baseline: 1.0649x; 1.0649x over previous
//
#include <hip/hip_runtime.h>

// Partial-CRF NLL, 4-producer/1-consumer scan, MX-fp8 K=128, group-8 coupling.
// 64 blocks x 320 threads = {wave0: consumer, waves1-4: producers (2 batches each)}.
// Block owns 16 chains = 8 batches x {all-paths, gold}.
//
// Numerics = R9 (absmax 0.0): true P = stored_fp8 x 2^eSum (uniform per chain).
// Tile 7 A-rows all E[.][1] -> D7 broadcasts w1pre; x exp(emit[t][1]) (4-deep
// global prefetch) -> ex = ilogb(w1) locally; csf = 2^-ex exact.
// fminf(.,440) clamp BEFORE fp8 pack is REQUIRED (R10 lesson: cvt_pk_fp8
// overflow is not verified-saturating; unclamped spread > 448 poisons eSum).
// Coupling: 16-slab ring; consumer polls 4 producer flags ONCE per 8 steps,
// releases once per 8; producers {poll, fence, flag} once per 8-slab group,
// double-buffered 8-step load sets (16-step load->use distance).

typedef short s16x4 __attribute__((ext_vector_type(4)));
typedef short s16x8 __attribute__((ext_vector_type(8)));
typedef float f32x4 __attribute__((ext_vector_type(4)));
typedef int   i32x8 __attribute__((ext_vector_type(8)));

constexpr int T = 512, L = 102;
constexpr int MS = 136;        // slab row stride (shorts)
constexpr int NS = 16;         // ring slabs
constexpr int SLAB = 16 * MS;  // shorts per slab

__device__ __forceinline__ float bf2f(short s) {
  return __uint_as_float(((unsigned)(unsigned short)s) << 16);
}
__device__ __forceinline__ float fp8tof(unsigned b) {  // e4m3fn, sign=0
  const int e = (b >> 3) & 15, m = b & 7;
  return e ? ldexpf((float)(8 + m), e - 10) : ldexpf((float)m, -9);
}

#define SC1 0x7F7F7F7F

// one tile epilogue: w = D*mult*csf, clamp 440 (REQUIRED), pack fp8, update
#define ETILE(Tt, FU)                                                        \
  {                                                                          \
    const float x0 = fminf(dd[Tt][0] * FU[4 * Tt + 0] * csf, 440.f);         \
    const float x1 = fminf(dd[Tt][1] * FU[4 * Tt + 1] * csf, 440.f);         \
    const float x2 = fminf(dd[Tt][2] * FU[4 * Tt + 2] * csf, 440.f);         \
    const float x3 = fminf(dd[Tt][3] * FU[4 * Tt + 3] * csf, 440.f);         \
    int d_ = __builtin_amdgcn_cvt_pk_fp8_f32(x0, x1, 0, false);              \
    d_ = __builtin_amdgcn_cvt_pk_fp8_f32(x2, x3, d_, true);                  \
    pkv[Tt] = mmv ? d_ : pkv[Tt];                                            \
  }

// One scan step t. SBn: slab short-offset for t+1 (prefetch into FL);
// TN: clamped t+4 for the e1 prefetch; FU: mult regs for this step;
// E1: rotating e1 register (holds raw emit[t][1]; reloaded for t+4).
#define STEP(SBn, TN, MMVv, FU, FL, E1)                                      \
  {                                                                          \
    const bool mmv = (MMVv) != 0;                                            \
    const float e1v = __expf(E1);                                            \
    const short* sln = mlb + (SBn) + c * MS + 32 * hi;                       \
    const s16x8 N0 = *(const s16x8*)(sln + 0);                               \
    const s16x8 N1 = *(const s16x8*)(sln + 8);                               \
    const s16x8 N2 = *(const s16x8*)(sln + 16);                              \
    const s16x4 N3 = *(const s16x4*)(sln + 24);                              \
    E1 = e1p[(size_t)(TN) * L];                                              \
    const f32x4 d7 = __builtin_amdgcn_mfma_scale_f32_16x16x128_f8f6f4(       \
        ea[7], pkv, zf, 0, 0, 0, SC1, 0, SC1);                               \
    f32x4 dd[7];                                                             \
    dd[0] = __builtin_amdgcn_mfma_scale_f32_16x16x128_f8f6f4(                \
        ea[0], pkv, zf, 0, 0, 0, SC1, 0, SC1);                               \
    dd[1] = __builtin_amdgcn_mfma_scale_f32_16x16x128_f8f6f4(                \
        ea[1], pkv, zf, 0, 0, 0, SC1, 0, SC1);                               \
    dd[2] = __builtin_amdgcn_mfma_scale_f32_16x16x128_f8f6f4(                \
        ea[2], pkv, zf, 0, 0, 0, SC1, 0, SC1);                               \
    dd[3] = __builtin_amdgcn_mfma_scale_f32_16x16x128_f8f6f4(                \
        ea[3], pkv, zf, 0, 0, 0, SC1, 0, SC1);                               \
    dd[4] = __builtin_amdgcn_mfma_scale_f32_16x16x128_f8f6f4(                \
        ea[4], pkv, zf, 0, 0, 0, SC1, 0, SC1);                               \
    dd[5] = __builtin_amdgcn_mfma_scale_f32_16x16x128_f8f6f4(                \
        ea[5], pkv, zf, 0, 0, 0, SC1, 0, SC1);                               \
    dd[6] = __builtin_amdgcn_mfma_scale_f32_16x16x128_f8f6f4(                \
        ea[6], pkv, zf, 0, 0, 0, SC1, 0, SC1);                               \
    const float w1 = d7[0] * e1v;                                            \
    const int ex = (int)(__float_as_uint(w1) >> 23) - 127;                   \
    const float csf = __uint_as_float((unsigned)(127 - ex) << 23);           \
    eSum += mmv ? ex : 0;                                                    \
    ETILE(0, FU) ETILE(1, FU) ETILE(2, FU) ETILE(3, FU)                      \
    ETILE(4, FU) ETILE(5, FU) ETILE(6, FU)                                   \
    _Pragma("unroll") for (int i = 0; i < 8; ++i) FL[i]      = bf2f(N0[i]);  \
    _Pragma("unroll") for (int i = 0; i < 8; ++i) FL[8 + i]  = bf2f(N1[i]);  \
    _Pragma("unroll") for (int i = 0; i < 8; ++i) FL[16 + i] = bf2f(N2[i]);  \
    _Pragma("unroll") for (int i = 0; i < 4; ++i) FL[24 + i] = bf2f(N3[i]);  \
  }

__global__ __launch_bounds__(320, 1)
void crf_scan(const float* __restrict__ emit,
              const float* __restrict__ trans,
              const unsigned char* __restrict__ mask_b,
              const unsigned char* __restrict__ um_b,
              float* __restrict__ partials)
{
  const int tid = threadIdx.x, wid = tid >> 6, lane = tid & 63;
  const int b8 = blockIdx.x * 8;
  // bool layout: um[0,0,1] always True -> byte1==1 iff uint8, else LE int32
  const int ush = (um_b[1] != 0) ? 0 : 2;

  __shared__ __align__(16) short Ml[NS][16][MS];
  __shared__ unsigned char Kmask[8][T];
  __shared__ int sflags[5];   // [0..3]: producer progress; [4]: consumer

  volatile int* pf0 = (volatile int*)&sflags[0];
  volatile int* pf1 = (volatile int*)&sflags[1];
  volatile int* pf2 = (volatile int*)&sflags[2];
  volatile int* pf3 = (volatile int*)&sflags[3];
  volatile int* cfv = (volatile int*)&sflags[4];

  if (wid != 0) {
    // ================= producer waves (wid 1..4, 2 batches each) =========
    const int p    = wid - 1;
    const int boff = 2 * p;
    const int tagp = 2 * lane;
    const int tagc = (tagp <= 100) ? tagp : 100;
    const bool tv  = (tagp <= 100);
    const int woff = 32 * (tagp / 28) + (tagp - 28 * (tagp / 28));
    const bool wok = (tagp < 112);

    if (lane == 0) sflags[p] = 0;
    for (int i = lane; i < 2 * T; i += 64) {       // my 2 Kmask rows
      const int bb_ = i >> 9, tt = i & 511;
      Kmask[boff + bb_][tt] =
          mask_b[(((size_t)(b8 + boff + bb_)) * T + tt) << ush];
    }

    struct SetG { float2 e[8][2]; uint2 u[8][2]; };
    SetG SA, SB;                                   // static names (rule #20)

    auto issueG = [&](int g, SetG& S) {
#pragma unroll
      for (int s = 0; s < 8; ++s) {
        const int tc = (g + s <= 511) ? (g + s) : 511;
#pragma unroll
        for (int i = 0; i < 2; ++i) {
          const size_t base = ((size_t)(b8 + boff + i) * T + tc) * (size_t)L;
          S.e[s][i] = *(const float2*)(emit + base + tagc);
          if (ush == 0) {
            const unsigned us =
                *(const unsigned short*)(um_b + base + tagc);
            S.u[s][i].x = us & 255u; S.u[s][i].y = us >> 8;
          } else {
            S.u[s][i] = *(const uint2*)(um_b + ((base + tagc) << 2));
          }
        }
      }
    };
    auto stageG = [&](int g, SetG& S) {
#pragma unroll
      for (int s = 0; s < 8; ++s) {
        if (g + s <= 511) {
          short* slab = &Ml[(g + s) & 15][0][0];
#pragma unroll
          for (int i = 0; i < 2; ++i) {
            const float e0 = tv ? __expf(S.e[s][i].x) : 0.f;
            const float e1_ = tv ? __expf(S.e[s][i].y) : 0.f;
            const float g0 = S.u[s][i].x ? e0 : 0.f;
            const float g1 = S.u[s][i].y ? e1_ : 0.f;
            unsigned pe, pg;
            asm("v_cvt_pk_bf16_f32 %0, %1, %2" : "=v"(pe) : "v"(e0), "v"(e1_));
            asm("v_cvt_pk_bf16_f32 %0, %1, %2" : "=v"(pg) : "v"(g0), "v"(g1));
            if (wok) {
              *(unsigned*)(slab + (2 * (boff + i))     * MS + woff) = pe;
              *(unsigned*)(slab + (2 * (boff + i) + 1) * MS + woff) = pg;
            }
          }
        }
      }
    };

    volatile int* myf = (p == 0) ? pf0 : (p == 1) ? pf1 : (p == 2) ? pf2 : pf3;
    __syncthreads();
    issueG(1, SA); issueG(9, SB);
    int csn = 0;

#define GBODY(gg, S)                                               \
    {                                                              \
      const int need = (gg) - 9;                                   \
      if (need > 0 && csn < need) {                                \
        int v; do { v = *cfv; } while (v < need);                  \
        csn = v;                                                   \
      }                                                            \
      stageG((gg), S);                                             \
      asm volatile("s_waitcnt lgkmcnt(0)" ::: "memory");           \
      if (lane == 0) *myf = ((gg) + 7 <= 511) ? (gg) + 7 : 511;    \
      issueG((gg) + 16, S);                                        \
    }
    for (int g = 1; g <= 497; g += 16) {
      GBODY(g, SA)
      GBODY(g + 8, SB)
    }
#undef GBODY
  } else {
    // ========================= consumer wave =========================
    if (lane == 0) sflags[4] = 0;
    __builtin_amdgcn_s_setprio(1);
    const int c = lane & 15, hi = lane >> 4;
    const int myb = c >> 1, batch = b8 + myb, goldc = c & 1;

    // A-frags fp8. Tiles 0..6: row c -> out-tag 28*(c>>2)+4*Tt+(c&3);
    // tile 7: all rows = E[.][1]. Byte j -> k-tag 28*hi+j (j<28; pad 0).
    i32x8 ea[8];
#pragma unroll
    for (int Tt = 0; Tt < 8; ++Tt) {
      const int gA = (Tt < 7) ? (28 * (c >> 2) + 4 * Tt + (c & 3)) : 1;
#pragma unroll
      for (int d8 = 0; d8 < 8; ++d8) {
        float v0 = 0.f, v1 = 0.f, v2 = 0.f, v3 = 0.f;
#pragma unroll
        for (int bq = 0; bq < 4; ++bq) {
          const int j = 4 * d8 + bq, ktag = 28 * hi + j;
          float e = 0.f;
          if (j < 28 && ktag < L && gA < L) e = __expf(trans[ktag * L + gA]);
          if (bq == 0) v0 = e; else if (bq == 1) v1 = e;
          else if (bq == 2) v2 = e; else v3 = e;
        }
        int dw = __builtin_amdgcn_cvt_pk_fp8_f32(v0, v1, 0, false);
        dw = __builtin_amdgcn_cvt_pk_fp8_f32(v2, v3, dw, true);
        ea[Tt][d8] = dw;
      }
    }

    // t = 0 init: P0 = exp(e0 + trans[START][tag]) (gold: um-gated),
    // normalized by 2^-ex0, ex0 = ilogb(P0[1]); eSum = ex0.
    i32x8 pkv = {0, 0, 0, 0, 0, 0, 0, 0};
    int eSum;
    const size_t e0b = (size_t)batch * T * L;
    {
      const float p01 = __expf(emit[e0b + 1] + trans[100 * L + 1]);
      const int ex0 = (int)(__float_as_uint(p01) >> 23) - 127;
      const float cs0 = __uint_as_float((unsigned)(127 - ex0) << 23);
      eSum = ex0;
#pragma unroll
      for (int Tt = 0; Tt < 7; ++Tt) {
        float w[4];
#pragma unroll
        for (int r = 0; r < 4; ++r) {
          const int tg = 28 * hi + 4 * Tt + r;
          float x = 0.f;
          if (tg < L) {
            x = __expf(emit[e0b + tg] + trans[100 * L + tg]);
            if (goldc && !um_b[(e0b + tg) << ush]) x = 0.f;
          }
          w[r] = fminf(x * cs0, 440.f);
        }
        int dw = __builtin_amdgcn_cvt_pk_fp8_f32(w[0], w[1], 0, false);
        dw = __builtin_amdgcn_cvt_pk_fp8_f32(w[2], w[3], dw, true);
        pkv[Tt] = dw;
      }
    }

    const short* mlb = &Ml[0][0][0];
    const unsigned* kmr = (const unsigned*)&Kmask[myb][0];
    const float* e1p = emit + e0b + 1;       // emit[batch][t][1] at e1p[t*L]
    const f32x4 zf = {0.f, 0.f, 0.f, 0.f};
    float fA[28], fB[28];
    float e1a, e1b, e1c, e1d;
    int seen = 0;

    __syncthreads();

    // e1 prefetch for t = 1..4 (independent of producers)
    e1a = e1p[(size_t)1 * L]; e1b = e1p[(size_t)2 * L];
    e1c = e1p[(size_t)3 * L]; e1d = e1p[(size_t)4 * L];

    {   // initial poll (slabs 1..9 ready) + preload fA from slab 1
      int v0, v1, v2, v3;
      do { v0 = *pf0; v1 = *pf1; v2 = *pf2; v3 = *pf3; }
      while (v0 < 9 || v1 < 9 || v2 < 9 || v3 < 9);
      int mn = v0 < v1 ? v0 : v1; mn = mn < v2 ? mn : v2;
      seen = mn < v3 ? mn : v3;
      int sb1_ = 1 * SLAB;
      asm volatile("" : "+v"(sb1_) : "v"(seen));
      const short* sln = mlb + sb1_ + c * MS + 32 * hi;
      const s16x8 N0 = *(const s16x8*)(sln + 0);
      const s16x8 N1 = *(const s16x8*)(sln + 8);
      const s16x8 N2 = *(const s16x8*)(sln + 16);
      const s16x4 N3 = *(const s16x4*)(sln + 24);
#pragma unroll
      for (int i = 0; i < 8; ++i) fA[i] = bf2f(N0[i]);
#pragma unroll
      for (int i = 0; i < 8; ++i) fA[8 + i] = bf2f(N1[i]);
#pragma unroll
      for (int i = 0; i < 8; ++i) fA[16 + i] = bf2f(N2[i]);
#pragma unroll
      for (int i = 0; i < 4; ++i) fA[24 + i] = bf2f(N3[i]);
    }

    for (int g = 1; g <= 497; g += 8) {
      if (seen < g + 8) {
        int v0, v1, v2, v3;
        do { v0 = *pf0; v1 = *pf1; v2 = *pf2; v3 = *pf3; }
        while (v0 < g + 8 || v1 < g + 8 || v2 < g + 8 || v3 < g + 8);
        int mn = v0 < v1 ? v0 : v1; mn = mn < v2 ? mn : v2;
        seen = mn < v3 ? mn : v3;
      }
      int s1_ = ((g + 1) & 15) * SLAB, s2_ = ((g + 2) & 15) * SLAB;
      int s3_ = ((g + 3) & 15) * SLAB, s4_ = ((g + 4) & 15) * SLAB;
      int s5_ = ((g + 5) & 15) * SLAB, s6_ = ((g + 6) & 15) * SLAB;
      int s7_ = ((g + 7) & 15) * SLAB, s8_ = ((g + 8) & 15) * SLAB;
      asm volatile("" : "+v"(s1_), "+v"(s2_), "+v"(s3_), "+v"(s4_),
                        "+v"(s5_), "+v"(s6_), "+v"(s7_), "+v"(s8_)
                   : "v"(seen));
      const int k2 = (g - 1) >> 2;                     // = 2k for g = 8k+1
      const unsigned wa = kmr[k2], wb = kmr[k2 + 1], wc = kmr[k2 + 2];
      const unsigned m0 = (wa >> 8) & 255u, m1 = (wa >> 16) & 255u;
      const unsigned m2 = wa >> 24;
      const unsigned m3 = wb & 255u, m4 = (wb >> 8) & 255u;
      const unsigned m5 = (wb >> 16) & 255u, m6 = wb >> 24;
      const unsigned m7 = wc & 255u;
      STEP(s1_, g + 4,  m0, fA, fB, e1a)
      STEP(s2_, g + 5,  m1, fB, fA, e1b)
      STEP(s3_, g + 6,  m2, fA, fB, e1c)
      STEP(s4_, g + 7,  m3, fB, fA, e1d)
      STEP(s5_, g + 8,  m4, fA, fB, e1a)
      STEP(s6_, g + 9,  m5, fB, fA, e1b)
      STEP(s7_, g + 10, m6, fA, fB, e1c)
      STEP(s8_, g + 11, m7, fB, fA, e1d)
      asm volatile("s_waitcnt lgkmcnt(0)" ::: "memory");
      if (lane == 0) *cfv = g + 7;
    }
    {   // tail: t = 505..511 (7 steps)
      if (seen < 511) {
        int v0, v1, v2, v3;
        do { v0 = *pf0; v1 = *pf1; v2 = *pf2; v3 = *pf3; }
        while (v0 < 511 || v1 < 511 || v2 < 511 || v3 < 511);
        seen = 511;
      }
      int s1_ = 10 * SLAB, s2_ = 11 * SLAB, s3_ = 12 * SLAB, s4_ = 13 * SLAB;
      int s5_ = 14 * SLAB, s6_ = 15 * SLAB, s7_ = 0 * SLAB;
      asm volatile("" : "+v"(s1_), "+v"(s2_), "+v"(s3_), "+v"(s4_),
                        "+v"(s5_), "+v"(s6_), "+v"(s7_)
                   : "v"(seen));
      const unsigned wa = kmr[126], wb = kmr[127];     // bytes 504..511
      const unsigned m0 = (wa >> 8) & 255u, m1 = (wa >> 16) & 255u;
      const unsigned m2 = wa >> 24;
      const unsigned m3 = wb & 255u, m4 = (wb >> 8) & 255u;
      const unsigned m5 = (wb >> 16) & 255u, m6 = wb >> 24;
      STEP(s1_, 509, m0, fA, fB, e1a)
      STEP(s2_, 510, m1, fB, fA, e1b)
      STEP(s3_, 511, m2, fA, fB, e1c)
      STEP(s4_, 511, m3, fB, fA, e1d)
      STEP(s5_, 511, m4, fA, fB, e1a)
      STEP(s6_, 511, m5, fB, fA, e1b)
      STEP(s7_, 511, m6, fA, fB, e1c)
    }

    // final: tot = sum_tag stored * exp(trans[tag][STOP]); sum the chain's
    // 4 hi-lanes; score = eSum*ln2 + log(tot).
    float tot = 0.f;
#pragma unroll
    for (int Tt = 0; Tt < 7; ++Tt) {
#pragma unroll
      for (int r = 0; r < 4; ++r) {
        const int tg = 28 * hi + 4 * Tt + r;
        if (tg < L) {
          const unsigned pb = ((unsigned)pkv[Tt] >> (8 * r)) & 255u;
          tot += fp8tof(pb) * __expf(trans[tg * L + 101]);
        }
      }
    }
    tot += __shfl_xor(tot, 16);
    tot += __shfl_xor(tot, 32);
    const float score = (float)eSum * 0.6931471805599453f + __logf(tot);
    float sgn = goldc ? -score : score;
    sgn += __shfl_xor(sgn, 1);
    sgn += __shfl_xor(sgn, 2);
    sgn += __shfl_xor(sgn, 4);
    sgn += __shfl_xor(sgn, 8);
    if (lane == 0) partials[blockIdx.x] = sgn;
  }
}

__global__ void reduce_partials(const float* __restrict__ part,
                                float* __restrict__ out) {
  float v = part[threadIdx.x];
#pragma unroll
  for (int s = 1; s < 64; s <<= 1) v += __shfl_xor(v, s);
  if (threadIdx.x == 0) out[0] = v;
}

extern "C" void kernel_launch(void* const* d_in, const int* in_sizes, int n_in,
                              void* d_out, int out_size, void* d_ws,
                              size_t ws_size, hipStream_t stream) {
  const float* emit = (const float*)d_in[0];
  const float* trn  = (const float*)d_in[1];
  const unsigned char* msk = (const unsigned char*)d_in[2];
  const unsigned char* umk = (const unsigned char*)d_in[3];
  float* out = (float*)d_out;
  float* pw  = (float*)d_ws;   // 64 block partials

  crf_scan<<<dim3(64), dim3(320), 0, stream>>>(emit, trn, msk, umk, pw);
  reduce_partials<<<dim3(1), dim3(64), 0, stream>>>(pw, out);
}